// Round 1
// baseline (2188.181 us; speedup 1.0000x reference)
//
#include <hip/hip_runtime.h>
#include <math.h>

#define M_TOK 2048
#define D_DIM 1024
#define H_DIM 1024
#define N_EXP 8
#define N_ROUTED 7
#define TT 8

// ---------------- routing: 1 wave per token ----------------
__global__ __launch_bounds__(256)
void routing_kernel(const float* __restrict__ x,
                    const float* __restrict__ Wg,
                    float* __restrict__ w_out,
                    int* __restrict__ cnt,
                    int* __restrict__ perm) {
  const int lane = threadIdx.x & 63;
  const int m = blockIdx.x * 4 + (threadIdx.x >> 6);
  if (m >= M_TOK) return;
  float acc[N_EXP];
#pragma unroll
  for (int n = 0; n < N_EXP; ++n) acc[n] = 0.f;
  const float* xr = x + (size_t)m * D_DIM;
  for (int d = lane; d < D_DIM; d += 64) {
    const float xv = xr[d];
    const float4 wa = *reinterpret_cast<const float4*>(Wg + (size_t)d * N_EXP);
    const float4 wb = *reinterpret_cast<const float4*>(Wg + (size_t)d * N_EXP + 4);
    acc[0] = fmaf(xv, wa.x, acc[0]);
    acc[1] = fmaf(xv, wa.y, acc[1]);
    acc[2] = fmaf(xv, wa.z, acc[2]);
    acc[3] = fmaf(xv, wa.w, acc[3]);
    acc[4] = fmaf(xv, wb.x, acc[4]);
    acc[5] = fmaf(xv, wb.y, acc[5]);
    acc[6] = fmaf(xv, wb.z, acc[6]);
    acc[7] = fmaf(xv, wb.w, acc[7]);
  }
#pragma unroll
  for (int n = 0; n < N_EXP; ++n) {
#pragma unroll
    for (int off = 32; off > 0; off >>= 1)
      acc[n] += __shfl_xor(acc[n], off, 64);
  }
  if (lane == 0) {
    // argmax over routed experts 0..6 (sigmoid is monotonic; bias kills slot 7).
    // jax top_k tie-break = lowest index -> strict '>' keeps first max.
    int bi = 0;
    float bl = acc[0];
#pragma unroll
    for (int n = 1; n < N_ROUTED; ++n) {
      if (acc[n] > bl) { bl = acc[n]; bi = n; }
    }
    const float s = 1.f / (1.f + expf(-bl));
    w_out[m] = s / (s + 1e-9f);
    const int pos = atomicAdd(&cnt[bi], 1);
    perm[bi * M_TOK + pos] = m;
  }
}

// ---------------- fused SwiGLU expert MLP ----------------
// 256 threads, TT=8 tokens per block. Thread owns 4 consecutive output
// columns (float4 loads/stores). LDS: x tile (32 KB) reused for h tile.
__global__ __launch_bounds__(256)
void expert_mlp_kernel(const float* __restrict__ x,
                       const float* __restrict__ Wl1,   // [N, D, 2H]
                       const float* __restrict__ Wl2,   // [N, H, D]
                       const int* __restrict__ perm,    // null => shared expert 7
                       const int* __restrict__ cnt,
                       float* __restrict__ yout) {      // raw (unweighted) per-token rows
  __shared__ float smem[TT * D_DIM];
  const int tid = threadIdx.x;
  int n, tok[TT];
  bool valid[TT];
  if (perm == nullptr) {
    n = N_EXP - 1;
    const int base = blockIdx.x * TT;
#pragma unroll
    for (int t = 0; t < TT; ++t) { tok[t] = base + t; valid[t] = true; }
  } else {
    n = blockIdx.y;
    const int c = cnt[n];
    const int base = blockIdx.x * TT;
    if (base >= c) return;
    const int* pl = perm + n * M_TOK;
#pragma unroll
    for (int t = 0; t < TT; ++t) {
      const int p = base + t;
      valid[t] = (p < c);
      tok[t] = pl[valid[t] ? p : 0];   // duplicate first token for tail slots
    }
  }

  // stage x rows into LDS (each thread: one float4 per row)
#pragma unroll
  for (int t = 0; t < TT; ++t) {
    reinterpret_cast<float4*>(smem + t * D_DIM)[tid] =
        reinterpret_cast<const float4*>(x + (size_t)tok[t] * D_DIM)[tid];
  }
  __syncthreads();

  // ---- layer 1: gu = x @ Wl1[n], thread owns columns 4*tid..4*tid+3 of g and u
  const float* W1 = Wl1 + (size_t)n * D_DIM * 2 * H_DIM;
  float g[4][TT], u[4][TT];
#pragma unroll
  for (int j = 0; j < 4; ++j)
#pragma unroll
    for (int t = 0; t < TT; ++t) { g[j][t] = 0.f; u[j][t] = 0.f; }

  for (int d = 0; d < D_DIM; ++d) {
    float xv[TT];
#pragma unroll
    for (int t = 0; t < TT; ++t) xv[t] = smem[t * D_DIM + d];  // LDS broadcast
    const float* wrow = W1 + (size_t)d * (2 * H_DIM);
    const float4 wg = reinterpret_cast<const float4*>(wrow)[tid];
    const float4 wu = reinterpret_cast<const float4*>(wrow + H_DIM)[tid];
#pragma unroll
    for (int t = 0; t < TT; ++t) {
      g[0][t] = fmaf(xv[t], wg.x, g[0][t]);
      g[1][t] = fmaf(xv[t], wg.y, g[1][t]);
      g[2][t] = fmaf(xv[t], wg.z, g[2][t]);
      g[3][t] = fmaf(xv[t], wg.w, g[3][t]);
      u[0][t] = fmaf(xv[t], wu.x, u[0][t]);
      u[1][t] = fmaf(xv[t], wu.y, u[1][t]);
      u[2][t] = fmaf(xv[t], wu.z, u[2][t]);
      u[3][t] = fmaf(xv[t], wu.w, u[3][t]);
    }
  }

  // ---- silu(g)*u
  float h[4][TT];
#pragma unroll
  for (int j = 0; j < 4; ++j)
#pragma unroll
    for (int t = 0; t < TT; ++t) {
      const float gv = g[j][t];
      const float sg = 1.f / (1.f + expf(-gv));
      h[j][t] = gv * sg * u[j][t];
    }
  __syncthreads();   // everyone done reading x tile
#pragma unroll
  for (int t = 0; t < TT; ++t) {
    reinterpret_cast<float4*>(smem + t * H_DIM)[tid] =
        make_float4(h[0][t], h[1][t], h[2][t], h[3][t]);
  }
  __syncthreads();

  // ---- layer 2: y = h @ Wl2[n]
  const float* W2 = Wl2 + (size_t)n * H_DIM * D_DIM;
  float acc[4][TT];
#pragma unroll
  for (int j = 0; j < 4; ++j)
#pragma unroll
    for (int t = 0; t < TT; ++t) acc[j][t] = 0.f;

  for (int hh = 0; hh < H_DIM; ++hh) {
    float hv[TT];
#pragma unroll
    for (int t = 0; t < TT; ++t) hv[t] = smem[t * H_DIM + hh];  // LDS broadcast
    const float4 wv = reinterpret_cast<const float4*>(W2 + (size_t)hh * D_DIM)[tid];
#pragma unroll
    for (int t = 0; t < TT; ++t) {
      acc[0][t] = fmaf(hv[t], wv.x, acc[0][t]);
      acc[1][t] = fmaf(hv[t], wv.y, acc[1][t]);
      acc[2][t] = fmaf(hv[t], wv.z, acc[2][t]);
      acc[3][t] = fmaf(hv[t], wv.w, acc[3][t]);
    }
  }

#pragma unroll
  for (int t = 0; t < TT; ++t) {
    if (valid[t]) {
      reinterpret_cast<float4*>(yout + (size_t)tok[t] * D_DIM)[tid] =
          make_float4(acc[0][t], acc[1][t], acc[2][t], acc[3][t]);
    }
  }
}

// ---------------- combine: y = y_shared + w * y_routed ----------------
__global__ __launch_bounds__(256)
void combine_kernel(const float* __restrict__ ys, const float* __restrict__ yr,
                    const float* __restrict__ w, float* __restrict__ out) {
  const int i = blockIdx.x * 256 + threadIdx.x;  // float4 index over M*D/4
  const int m = i >> 8;                          // D/4 = 256 float4 per row
  const float4 a = reinterpret_cast<const float4*>(ys)[i];
  const float4 b = reinterpret_cast<const float4*>(yr)[i];
  const float wm = w[m];
  float4 o;
  o.x = fmaf(wm, b.x, a.x);
  o.y = fmaf(wm, b.y, a.y);
  o.z = fmaf(wm, b.z, a.z);
  o.w = fmaf(wm, b.w, a.w);
  reinterpret_cast<float4*>(out)[i] = o;
}

extern "C" void kernel_launch(void* const* d_in, const int* in_sizes, int n_in,
                              void* d_out, int out_size, void* d_ws, size_t ws_size,
                              hipStream_t stream) {
  const float* x   = (const float*)d_in[0];   // [2,1024,1024] f32
  const float* Wg  = (const float*)d_in[1];   // [1024,8]
  const float* Wl1 = (const float*)d_in[2];   // [8,1024,2048]
  const float* Wl2 = (const float*)d_in[3];   // [8,1024,1024]
  float* out = (float*)d_out;                 // [2,1024,1024] f32

  char* ws = (char*)d_ws;
  int*   cnt  = (int*)(ws + 0);               // 8 ints
  float* wtok = (float*)(ws + 4096);          // 2048 f32 gate weights
  int*   perm = (int*)(ws + 65536);           // 8*2048 ints (64 KB)
  float* y_s  = (float*)(ws + (1u << 20));    // 8 MB shared-expert out
  float* y_r  = (float*)(ws + (16u << 20));   // 8 MB routed-expert out

  hipMemsetAsync(cnt, 0, N_EXP * sizeof(int), stream);
  routing_kernel<<<M_TOK / 4, 256, 0, stream>>>(x, Wg, wtok, cnt, perm);
  // shared expert (id 7) over all tokens
  expert_mlp_kernel<<<dim3(M_TOK / TT, 1), 256, 0, stream>>>(
      x, Wl1, Wl2, nullptr, nullptr, y_s);
  // routed experts over compacted lists
  expert_mlp_kernel<<<dim3(M_TOK / TT, N_ROUTED), 256, 0, stream>>>(
      x, Wl1, Wl2, perm, cnt, y_r);
  combine_kernel<<<(M_TOK * D_DIM / 4) / 256, 256, 0, stream>>>(y_s, y_r, wtok, out);
}

// Round 3
// 335.752 us; speedup vs baseline: 6.5173x; 6.5173x over previous
//
#include <hip/hip_runtime.h>
#include <hip/hip_bf16.h>
#include <math.h>

#define M_TOK 2048
#define D_DIM 1024
#define H_DIM 1024
#define N_EXP 8
#define N_ROUTED 7

typedef __hip_bfloat16 bf16;
typedef float f32x4 __attribute__((ext_vector_type(4)));
typedef short bf16x8 __attribute__((ext_vector_type(8)));

#define GLOAD16(gp, lp)                                                     \
  __builtin_amdgcn_global_load_lds(                                         \
      (const __attribute__((address_space(1))) void*)(gp),                  \
      (__attribute__((address_space(3))) void*)(lp), 16, 0, 0)

// ---------------- routing: 1 wave per token ----------------
__global__ __launch_bounds__(256)
void routing_kernel(const float* __restrict__ x,
                    const float* __restrict__ Wg,
                    float* __restrict__ w_out,
                    int* __restrict__ cnt,
                    int* __restrict__ perm) {
  const int lane = threadIdx.x & 63;
  const int m = blockIdx.x * 4 + (threadIdx.x >> 6);
  if (m >= M_TOK) return;
  float acc[N_EXP];
#pragma unroll
  for (int n = 0; n < N_EXP; ++n) acc[n] = 0.f;
  const float* xr = x + (size_t)m * D_DIM;
  for (int d = lane; d < D_DIM; d += 64) {
    const float xv = xr[d];
    const float4 wa = *reinterpret_cast<const float4*>(Wg + (size_t)d * N_EXP);
    const float4 wb = *reinterpret_cast<const float4*>(Wg + (size_t)d * N_EXP + 4);
    acc[0] = fmaf(xv, wa.x, acc[0]);
    acc[1] = fmaf(xv, wa.y, acc[1]);
    acc[2] = fmaf(xv, wa.z, acc[2]);
    acc[3] = fmaf(xv, wa.w, acc[3]);
    acc[4] = fmaf(xv, wb.x, acc[4]);
    acc[5] = fmaf(xv, wb.y, acc[5]);
    acc[6] = fmaf(xv, wb.z, acc[6]);
    acc[7] = fmaf(xv, wb.w, acc[7]);
  }
#pragma unroll
  for (int n = 0; n < N_EXP; ++n) {
#pragma unroll
    for (int off = 32; off > 0; off >>= 1)
      acc[n] += __shfl_xor(acc[n], off, 64);
  }
  if (lane == 0) {
    int bi = 0;
    float bl = acc[0];
#pragma unroll
    for (int n = 1; n < N_ROUTED; ++n) {
      if (acc[n] > bl) { bl = acc[n]; bi = n; }
    }
    const float s = 1.f / (1.f + expf(-bl));
    w_out[m] = s / (s + 1e-9f);
    const int pos = atomicAdd(&cnt[bi], 1);
    perm[bi * M_TOK + pos] = m;
  }
}

// ---------------- f32 -> bf16 convert (x) ----------------
__global__ __launch_bounds__(256)
void convx_kernel(const float* __restrict__ in, bf16* __restrict__ outb) {
  const int i = blockIdx.x * 256 + threadIdx.x;  // 8 elements each
  const float4 a = reinterpret_cast<const float4*>(in)[i * 2];
  const float4 b = reinterpret_cast<const float4*>(in)[i * 2 + 1];
  union { bf16 h[8]; uint4 q; } u;
  u.h[0] = __float2bfloat16(a.x); u.h[1] = __float2bfloat16(a.y);
  u.h[2] = __float2bfloat16(a.z); u.h[3] = __float2bfloat16(a.w);
  u.h[4] = __float2bfloat16(b.x); u.h[5] = __float2bfloat16(b.y);
  u.h[6] = __float2bfloat16(b.z); u.h[7] = __float2bfloat16(b.w);
  reinterpret_cast<uint4*>(outb)[i] = u.q;
}

// ---------- f32 [z][R][C] -> bf16 [z][C][R] transpose+convert ----------
__global__ __launch_bounds__(256)
void transconv_kernel(const float* __restrict__ in, bf16* __restrict__ outb,
                      int R, int C) {
  __shared__ float tile[32][33];
  const float* inp = in + (size_t)blockIdx.z * R * C;
  bf16* outp = outb + (size_t)blockIdx.z * R * C;
  const int tx = threadIdx.x & 31, ty = threadIdx.x >> 5;
  const int c0 = blockIdx.x * 32;
  const int r0 = blockIdx.y * 32;
#pragma unroll
  for (int rep = 0; rep < 4; ++rep)
    tile[ty + rep * 8][tx] = inp[(size_t)(r0 + ty + rep * 8) * C + c0 + tx];
  __syncthreads();
#pragma unroll
  for (int rep = 0; rep < 4; ++rep)
    outp[(size_t)(c0 + ty + rep * 8) * R + r0 + tx] =
        __float2bfloat16(tile[tx][ty + rep * 8]);
}

// ---------------- layer 1: gu = x @ W1, h = silu(g)*u ----------------
// BM=128, BN=64 (g) + paired 64 (u), BK=32. 4 waves (2x2), wave tile 64x32.
__global__ __launch_bounds__(256)
void l1_kernel(const bf16* __restrict__ xb,
               const bf16* __restrict__ W1t,   // [8][2048][1024]
               const int* __restrict__ perm,
               const int* __restrict__ cnt,
               bf16* __restrict__ hbuf) {      // [8][2048][1024]
  const int n = blockIdx.z;
  const int mt = blockIdx.x;          // 16
  const int nt = blockIdx.y;          // 16 (64 g-cols each)
  const int c = (n == N_EXP - 1) ? M_TOK : cnt[n];
  if (mt * 128 >= c) return;

  __shared__ bf16 sA[128 * 32];   // 8KB
  __shared__ bf16 sBg[64 * 32];   // 4KB
  __shared__ bf16 sBu[64 * 32];   // 4KB

  const int tid = threadIdx.x;
  const int ar = tid >> 2;             // 0..63
  const int kseg = (tid & 3) * 8;      // element offset in k

  const int row0 = mt * 128 + ar;
  const int row1 = row0 + 64;
  int tok0, tok1;
  if (n == N_EXP - 1) { tok0 = row0; tok1 = row1; }
  else {
    tok0 = perm[n * M_TOK + (row0 < c ? row0 : 0)];
    tok1 = perm[n * M_TOK + (row1 < c ? row1 : 0)];
  }
  const bf16* ga0 = xb + (size_t)tok0 * D_DIM + kseg;
  const bf16* ga1 = xb + (size_t)tok1 * D_DIM + kseg;
  const bf16* gbg = W1t + ((size_t)n * 2048 + nt * 64 + ar) * D_DIM + kseg;
  const bf16* gbu = gbg + (size_t)H_DIM * D_DIM;
  bf16* lA0 = &sA[tid * 8];
  bf16* lA1 = &sA[2048 + tid * 8];
  bf16* lBg = &sBg[tid * 8];
  bf16* lBu = &sBu[tid * 8];

  const int lane = tid & 63;
  const int wid = tid >> 6;
  const int wm = wid >> 1, wn = wid & 1;
  const int l15 = lane & 15, lhi = lane >> 4;

  f32x4 accg[4][2], accu[4][2];
#pragma unroll
  for (int i = 0; i < 4; ++i)
#pragma unroll
    for (int j = 0; j < 2; ++j) {
      accg[i][j] = (f32x4){0.f, 0.f, 0.f, 0.f};
      accu[i][j] = (f32x4){0.f, 0.f, 0.f, 0.f};
    }

  for (int kt = 0; kt < D_DIM / 32; ++kt) {
    GLOAD16(ga0, lA0); GLOAD16(ga1, lA1);
    GLOAD16(gbg, lBg); GLOAD16(gbu, lBu);
    ga0 += 32; ga1 += 32; gbg += 32; gbu += 32;
    __syncthreads();
    bf16x8 a[4], bg[2], bu[2];
#pragma unroll
    for (int fm = 0; fm < 4; ++fm)
      a[fm] = *reinterpret_cast<const bf16x8*>(
          &sA[(wm * 64 + fm * 16 + l15) * 32 + lhi * 8]);
#pragma unroll
    for (int fn = 0; fn < 2; ++fn) {
      bg[fn] = *reinterpret_cast<const bf16x8*>(
          &sBg[(wn * 32 + fn * 16 + l15) * 32 + lhi * 8]);
      bu[fn] = *reinterpret_cast<const bf16x8*>(
          &sBu[(wn * 32 + fn * 16 + l15) * 32 + lhi * 8]);
    }
#pragma unroll
    for (int fm = 0; fm < 4; ++fm)
#pragma unroll
      for (int fn = 0; fn < 2; ++fn) {
        accg[fm][fn] = __builtin_amdgcn_mfma_f32_16x16x32_bf16(
            a[fm], bg[fn], accg[fm][fn], 0, 0, 0);
        accu[fm][fn] = __builtin_amdgcn_mfma_f32_16x16x32_bf16(
            a[fm], bu[fn], accu[fm][fn], 0, 0, 0);
      }
    __syncthreads();
  }

  bf16* hp = hbuf + (size_t)n * M_TOK * H_DIM;
#pragma unroll
  for (int fm = 0; fm < 4; ++fm)
#pragma unroll
    for (int fn = 0; fn < 2; ++fn)
#pragma unroll
      for (int r = 0; r < 4; ++r) {
        const int mrow = mt * 128 + wm * 64 + fm * 16 + lhi * 4 + r;
        const int col = nt * 64 + wn * 32 + fn * 16 + l15;
        const float g = accg[fm][fn][r];
        const float u = accu[fm][fn][r];
        const float h = g * u / (1.f + __expf(-g));
        hp[(size_t)mrow * H_DIM + col] = __float2bfloat16(h);
      }
}

// ---------------- layer 2: y += w * (h @ W2) ----------------
// BM=128, BN=64, BK=32. 4 waves (2x2), wave tile 64x32.
__global__ __launch_bounds__(256)
void l2_kernel(const bf16* __restrict__ hbuf,   // [8][2048][1024]
               const bf16* __restrict__ W2t,    // [8][1024 d][1024 h]
               const int* __restrict__ perm,
               const int* __restrict__ cnt,
               const float* __restrict__ wtok,
               float* __restrict__ out) {
  const int n = blockIdx.z;
  const int mt = blockIdx.x;          // 16
  const int nt = blockIdx.y;          // 16 (64 d-cols each)
  const int c = (n == N_EXP - 1) ? M_TOK : cnt[n];
  if (mt * 128 >= c) return;

  __shared__ bf16 sA[128 * 32];   // 8KB
  __shared__ bf16 sB[64 * 32];    // 4KB

  const int tid = threadIdx.x;
  const int ar = tid >> 2;
  const int kseg = (tid & 3) * 8;

  const bf16* hp = hbuf + (size_t)n * M_TOK * H_DIM;
  const bf16* ga0 = hp + (size_t)(mt * 128 + ar) * H_DIM + kseg;
  const bf16* ga1 = ga0 + (size_t)64 * H_DIM;
  const bf16* gb = W2t + ((size_t)n * D_DIM + nt * 64 + ar) * H_DIM + kseg;
  bf16* lA0 = &sA[tid * 8];
  bf16* lA1 = &sA[2048 + tid * 8];
  bf16* lB = &sB[tid * 8];

  const int lane = tid & 63;
  const int wid = tid >> 6;
  const int wm = wid >> 1, wn = wid & 1;
  const int l15 = lane & 15, lhi = lane >> 4;

  f32x4 acc[4][2];
#pragma unroll
  for (int i = 0; i < 4; ++i)
#pragma unroll
    for (int j = 0; j < 2; ++j) acc[i][j] = (f32x4){0.f, 0.f, 0.f, 0.f};

  for (int kt = 0; kt < H_DIM / 32; ++kt) {
    GLOAD16(ga0, lA0); GLOAD16(ga1, lA1); GLOAD16(gb, lB);
    ga0 += 32; ga1 += 32; gb += 32;
    __syncthreads();
    bf16x8 a[4], b[2];
#pragma unroll
    for (int fm = 0; fm < 4; ++fm)
      a[fm] = *reinterpret_cast<const bf16x8*>(
          &sA[(wm * 64 + fm * 16 + l15) * 32 + lhi * 8]);
#pragma unroll
    for (int fn = 0; fn < 2; ++fn)
      b[fn] = *reinterpret_cast<const bf16x8*>(
          &sB[(wn * 32 + fn * 16 + l15) * 32 + lhi * 8]);
#pragma unroll
    for (int fm = 0; fm < 4; ++fm)
#pragma unroll
      for (int fn = 0; fn < 2; ++fn)
        acc[fm][fn] = __builtin_amdgcn_mfma_f32_16x16x32_bf16(
            a[fm], b[fn], acc[fm][fn], 0, 0, 0);
    __syncthreads();
  }

#pragma unroll
  for (int fm = 0; fm < 4; ++fm)
#pragma unroll
    for (int r = 0; r < 4; ++r) {
      const int mrow = mt * 128 + wm * 64 + fm * 16 + lhi * 4 + r;
      if (mrow < c) {
        const int tok = (n == N_EXP - 1) ? mrow : perm[n * M_TOK + mrow];
        const float wt = (n == N_EXP - 1) ? 1.f : wtok[tok];
        const size_t base = (size_t)tok * D_DIM + nt * 64 + wn * 32 + l15;
        atomicAdd(&out[base], wt * acc[fm][0][r]);
        atomicAdd(&out[base + 16], wt * acc[fm][1][r]);
      }
    }
}

extern "C" void kernel_launch(void* const* d_in, const int* in_sizes, int n_in,
                              void* d_out, int out_size, void* d_ws, size_t ws_size,
                              hipStream_t stream) {
  const float* x   = (const float*)d_in[0];   // [2,1024,1024] f32
  const float* Wg  = (const float*)d_in[1];   // [1024,8]
  const float* Wl1 = (const float*)d_in[2];   // [8,1024,2048]
  const float* Wl2 = (const float*)d_in[3];   // [8,1024,1024]
  float* out = (float*)d_out;                 // [2,1024,1024] f32

  char* ws = (char*)d_ws;
  int*   cnt  = (int*)(ws + 0);                        // 32 B
  float* wtok = (float*)(ws + 1024);                   // 8 KB
  int*   perm = (int*)(ws + 16384);                    // 64 KB
  bf16*  xb   = (bf16*)(ws + (1ull << 20));            // 4 MB
  bf16*  W1t  = (bf16*)(ws + (8ull << 20));            // 32 MB
  bf16*  W2t  = (bf16*)(ws + (40ull << 20));           // 16 MB
  bf16*  hbuf = (bf16*)(ws + (56ull << 20));           // 32 MB

  hipMemsetAsync(cnt, 0, N_EXP * sizeof(int), stream);
  hipMemsetAsync(out, 0, (size_t)M_TOK * D_DIM * sizeof(float), stream);

  convx_kernel<<<M_TOK * D_DIM / 8 / 256, 256, 0, stream>>>(x, xb);
  transconv_kernel<<<dim3(2 * H_DIM / 32, D_DIM / 32, N_EXP), 256, 0, stream>>>(
      Wl1, W1t, D_DIM, 2 * H_DIM);
  transconv_kernel<<<dim3(D_DIM / 32, H_DIM / 32, N_EXP), 256, 0, stream>>>(
      Wl2, W2t, H_DIM, D_DIM);
  routing_kernel<<<M_TOK / 4, 256, 0, stream>>>(x, Wg, wtok, cnt, perm);

  l1_kernel<<<dim3(16, 16, N_EXP), 256, 0, stream>>>(xb, W1t, perm, cnt, hbuf);
  l2_kernel<<<dim3(16, 16, N_EXP), 256, 0, stream>>>(hbuf, W2t, perm, cnt, wtok, out);
}

// Round 4
// 246.808 us; speedup vs baseline: 8.8659x; 1.3604x over previous
//
#include <hip/hip_runtime.h>
#include <hip/hip_bf16.h>
#include <math.h>

#define M_TOK 2048
#define D_DIM 1024
#define H_DIM 1024
#define N_EXP 8
#define N_ROUTED 7
#define MAXT 40

typedef __hip_bfloat16 bf16;
typedef float f32x4 __attribute__((ext_vector_type(4)));
typedef short bf16x8 __attribute__((ext_vector_type(8)));

#define GLOAD16(gp, lp)                                                     \
  __builtin_amdgcn_global_load_lds(                                         \
      (const __attribute__((address_space(1))) void*)(gp),                  \
      (__attribute__((address_space(3))) void*)(lp), 16, 0, 0)

// ---------------- routing: 1 wave per token ----------------
__global__ __launch_bounds__(256)
void routing_kernel(const float* __restrict__ x,
                    const float* __restrict__ Wg,
                    float* __restrict__ w_out,
                    int* __restrict__ cnt,
                    int* __restrict__ perm) {
  const int lane = threadIdx.x & 63;
  const int m = blockIdx.x * 4 + (threadIdx.x >> 6);
  if (m >= M_TOK) return;
  float acc[N_EXP];
#pragma unroll
  for (int n = 0; n < N_EXP; ++n) acc[n] = 0.f;
  const float* xr = x + (size_t)m * D_DIM;
  for (int d = lane; d < D_DIM; d += 64) {
    const float xv = xr[d];
    const float4 wa = *reinterpret_cast<const float4*>(Wg + (size_t)d * N_EXP);
    const float4 wb = *reinterpret_cast<const float4*>(Wg + (size_t)d * N_EXP + 4);
    acc[0] = fmaf(xv, wa.x, acc[0]);
    acc[1] = fmaf(xv, wa.y, acc[1]);
    acc[2] = fmaf(xv, wa.z, acc[2]);
    acc[3] = fmaf(xv, wa.w, acc[3]);
    acc[4] = fmaf(xv, wb.x, acc[4]);
    acc[5] = fmaf(xv, wb.y, acc[5]);
    acc[6] = fmaf(xv, wb.z, acc[6]);
    acc[7] = fmaf(xv, wb.w, acc[7]);
  }
#pragma unroll
  for (int n = 0; n < N_EXP; ++n) {
#pragma unroll
    for (int off = 32; off > 0; off >>= 1)
      acc[n] += __shfl_xor(acc[n], off, 64);
  }
  if (lane == 0) {
    int bi = 0;
    float bl = acc[0];
#pragma unroll
    for (int n = 1; n < N_ROUTED; ++n) {
      if (acc[n] > bl) { bl = acc[n]; bi = n; }
    }
    const float s = 1.f / (1.f + expf(-bl));
    w_out[m] = s / (s + 1e-9f);
    const int pos = atomicAdd(&cnt[bi], 1);
    perm[bi * M_TOK + pos] = m;
  }
}

// ---------------- tile map: compact active (expert,row0) tiles ----------------
__global__ void tilemap_kernel(const int* __restrict__ cnt,
                               int* __restrict__ tmap, int* __restrict__ ntiles) {
  if (threadIdx.x == 0 && blockIdx.x == 0) {
    int t = 0;
    for (int n = 0; n < N_ROUTED; ++n) {
      const int c = cnt[n];
      for (int r = 0; r < c; r += 128) { tmap[2 * t] = n; tmap[2 * t + 1] = r; ++t; }
    }
    for (int r = 0; r < M_TOK; r += 128) { tmap[2 * t] = N_EXP - 1; tmap[2 * t + 1] = r; ++t; }
    ntiles[0] = t;
    for (int u = t; u < MAXT; ++u) { tmap[2 * u] = 0; tmap[2 * u + 1] = 0; }
  }
}

// ---------------- f32 -> bf16 convert (x) ----------------
__global__ __launch_bounds__(256)
void convx_kernel(const float* __restrict__ in, bf16* __restrict__ outb) {
  const int i = blockIdx.x * 256 + threadIdx.x;  // 8 elements each
  const float4 a = reinterpret_cast<const float4*>(in)[i * 2];
  const float4 b = reinterpret_cast<const float4*>(in)[i * 2 + 1];
  union { bf16 h[8]; uint4 q; } u;
  u.h[0] = __float2bfloat16(a.x); u.h[1] = __float2bfloat16(a.y);
  u.h[2] = __float2bfloat16(a.z); u.h[3] = __float2bfloat16(a.w);
  u.h[4] = __float2bfloat16(b.x); u.h[5] = __float2bfloat16(b.y);
  u.h[6] = __float2bfloat16(b.z); u.h[7] = __float2bfloat16(b.w);
  reinterpret_cast<uint4*>(outb)[i] = u.q;
}

// ---------- f32 [z][R][C] -> bf16 [z][C][R], 64x64 tile, 16B stores ----------
__global__ __launch_bounds__(256)
void transconv_kernel(const float* __restrict__ in, bf16* __restrict__ outb,
                      int R, int C) {
  __shared__ float tile[64][65];
  const int t = threadIdx.x;
  const float* inp = in + (size_t)blockIdx.z * R * C;
  bf16* outp = outb + (size_t)blockIdx.z * R * C;
  const int c0 = blockIdx.x * 64, r0 = blockIdx.y * 64;
  const int lr = t >> 4, lc4 = (t & 15) * 4;
#pragma unroll
  for (int rep = 0; rep < 4; ++rep) {
    const float4 v = *reinterpret_cast<const float4*>(
        inp + (size_t)(r0 + lr + rep * 16) * C + c0 + lc4);
    float* dst = &tile[lr + rep * 16][lc4];
    dst[0] = v.x; dst[1] = v.y; dst[2] = v.z; dst[3] = v.w;
  }
  __syncthreads();
  const int seg = t & 7;
#pragma unroll
  for (int rep = 0; rep < 2; ++rep) {
    const int oc = (t >> 3) + rep * 32;
    union { bf16 h[8]; uint4 q; } u;
#pragma unroll
    for (int j = 0; j < 8; ++j) u.h[j] = __float2bfloat16(tile[seg * 8 + j][oc]);
    *reinterpret_cast<uint4*>(outp + (size_t)(c0 + oc) * R + r0 + seg * 8) = u.q;
  }
}

// ================= layer 1: h = silu(x@W1g) * (x@W1u) =================
// BM=128 rows, 64 h-cols (64 g + 64 u B-rows), BK=64. 4 waves 2x2.
// Double-buffered LDS (two distinct arrays), 1 barrier per K-step.
// LDS elem layout per buffer: A[128][64] @0, Bg[64][64] @8192, Bu @12288.
// Swizzle: logical (row, slot s of 8 bf16) stored at slot s^(row&7).
__global__ __launch_bounds__(256, 2)
void l1_kernel(const bf16* __restrict__ xb,
               const bf16* __restrict__ W1t,   // [8][2048][1024]
               const int* __restrict__ perm,
               const int* __restrict__ cnt,
               const int* __restrict__ tmap,
               const int* __restrict__ ntiles,
               bf16* __restrict__ hbuf) {      // [8][2048][1024]
  const int ti = blockIdx.y;
  if (ti >= ntiles[0]) return;
  const int n = tmap[2 * ti], row0 = tmap[2 * ti + 1];
  const int nt = blockIdx.x;
  const int c = (n == N_EXP - 1) ? M_TOK : cnt[n];

  __shared__ bf16 L0[16384];
  __shared__ bf16 L1[16384];

  const int t = threadIdx.x;
  const int trow = t >> 3;                       // row within 32-row round
  const int gk = ((t & 7) ^ (trow & 7)) * 8;     // swizzled source k-offset

  int tokr[4];
#pragma unroll
  for (int p = 0; p < 4; ++p) {
    const int lr = row0 + p * 32 + trow;
    tokr[p] = (n == N_EXP - 1) ? lr : perm[n * M_TOK + (lr < c ? lr : row0)];
  }
  const bf16* gA0 = xb + (size_t)tokr[0] * D_DIM + gk;
  const bf16* gA1 = xb + (size_t)tokr[1] * D_DIM + gk;
  const bf16* gA2 = xb + (size_t)tokr[2] * D_DIM + gk;
  const bf16* gA3 = xb + (size_t)tokr[3] * D_DIM + gk;
  const bf16* gBg0 = W1t + ((size_t)n * 2048 + nt * 64 + trow) * D_DIM + gk;
  const bf16* gBg1 = gBg0 + (size_t)32 * D_DIM;
  const bf16* gBu0 = gBg0 + (size_t)H_DIM * D_DIM;
  const bf16* gBu1 = gBg1 + (size_t)H_DIM * D_DIM;

#define L1_STAGE(BUF, KT) do {                                   \
    const int ko = (KT) * 64;                                    \
    GLOAD16(gA0 + ko, &BUF[(0 * 256 + t) * 8]);                  \
    GLOAD16(gA1 + ko, &BUF[(1 * 256 + t) * 8]);                  \
    GLOAD16(gA2 + ko, &BUF[(2 * 256 + t) * 8]);                  \
    GLOAD16(gA3 + ko, &BUF[(3 * 256 + t) * 8]);                  \
    GLOAD16(gBg0 + ko, &BUF[8192 + (0 * 256 + t) * 8]);          \
    GLOAD16(gBg1 + ko, &BUF[8192 + (1 * 256 + t) * 8]);          \
    GLOAD16(gBu0 + ko, &BUF[12288 + (0 * 256 + t) * 8]);         \
    GLOAD16(gBu1 + ko, &BUF[12288 + (1 * 256 + t) * 8]);         \
  } while (0)

  const int lane = t & 63, wid = t >> 6;
  const int wm = wid >> 1, wn = wid & 1;
  const int l15 = lane & 15, lhi = lane >> 4, l7 = l15 & 7;

  f32x4 accg[4][2], accu[4][2];
#pragma unroll
  for (int i = 0; i < 4; ++i)
#pragma unroll
    for (int j = 0; j < 2; ++j) {
      accg[i][j] = (f32x4){0.f, 0.f, 0.f, 0.f};
      accu[i][j] = (f32x4){0.f, 0.f, 0.f, 0.f};
    }

#define L1_COMPUTE(BUF) do {                                                   \
    bf16x8 a[4][2], bg[2][2], bu[2][2];                                        \
    _Pragma("unroll") for (int kk = 0; kk < 2; ++kk) {                         \
      const int sl = ((kk * 4 + lhi) ^ l7) * 8;                                \
      _Pragma("unroll") for (int fm = 0; fm < 4; ++fm)                         \
        a[fm][kk] = *reinterpret_cast<const bf16x8*>(                          \
            &BUF[(wm * 64 + fm * 16 + l15) * 64 + sl]);                        \
      _Pragma("unroll") for (int fn = 0; fn < 2; ++fn) {                       \
        bg[fn][kk] = *reinterpret_cast<const bf16x8*>(                         \
            &BUF[8192 + (wn * 32 + fn * 16 + l15) * 64 + sl]);                 \
        bu[fn][kk] = *reinterpret_cast<const bf16x8*>(                         \
            &BUF[12288 + (wn * 32 + fn * 16 + l15) * 64 + sl]);                \
      }                                                                        \
    }                                                                          \
    _Pragma("unroll") for (int kk = 0; kk < 2; ++kk)                           \
    _Pragma("unroll") for (int fm = 0; fm < 4; ++fm)                           \
    _Pragma("unroll") for (int fn = 0; fn < 2; ++fn) {                         \
      accg[fm][fn] = __builtin_amdgcn_mfma_f32_16x16x32_bf16(                  \
          a[fm][kk], bg[fn][kk], accg[fm][fn], 0, 0, 0);                       \
      accu[fm][fn] = __builtin_amdgcn_mfma_f32_16x16x32_bf16(                  \
          a[fm][kk], bu[fn][kk], accu[fm][fn], 0, 0, 0);                       \
    }                                                                          \
  } while (0)

  L1_STAGE(L0, 0);
  __syncthreads();
  for (int it = 0; it < 8; ++it) {
    L1_STAGE(L1, 2 * it + 1);
    L1_COMPUTE(L0);
    __syncthreads();
    if (it < 7) L1_STAGE(L0, 2 * it + 2);
    L1_COMPUTE(L1);
    __syncthreads();
  }

  bf16* hp = hbuf + (size_t)n * M_TOK * H_DIM;
#pragma unroll
  for (int fm = 0; fm < 4; ++fm)
#pragma unroll
    for (int fn = 0; fn < 2; ++fn)
#pragma unroll
      for (int r = 0; r < 4; ++r) {
        const int mrow = row0 + wm * 64 + fm * 16 + lhi * 4 + r;
        const int col = nt * 64 + wn * 32 + fn * 16 + l15;
        const float g = accg[fm][fn][r];
        const float u = accu[fm][fn][r];
        const float h = g * u / (1.f + __expf(-g));
        hp[(size_t)mrow * H_DIM + col] = __float2bfloat16(h);
      }
#undef L1_STAGE
#undef L1_COMPUTE
}

// ================= layer 2: out += w * (h @ W2) =================
// BM=128, BN=64, BK=64. 4 waves 2x2 (wave 64x32). Dbuf, 1 barrier/K-step.
// LDS per buffer: A[128][64] @0, B[64][64] @8192.
__global__ __launch_bounds__(256, 4)
void l2_kernel(const bf16* __restrict__ hbuf,
               const bf16* __restrict__ W2t,    // [8][1024 d][1024 h]
               const int* __restrict__ perm,
               const int* __restrict__ cnt,
               const int* __restrict__ tmap,
               const int* __restrict__ ntiles,
               const float* __restrict__ wtok,
               float* __restrict__ out) {
  const int ti = blockIdx.y;
  if (ti >= ntiles[0]) return;
  const int n = tmap[2 * ti], row0 = tmap[2 * ti + 1];
  const int nt = blockIdx.x;
  const int c = (n == N_EXP - 1) ? M_TOK : cnt[n];

  __shared__ bf16 L0[12288];
  __shared__ bf16 L1[12288];

  const int t = threadIdx.x;
  const int trow = t >> 3;
  const int gk = ((t & 7) ^ (trow & 7)) * 8;

  const bf16* hp = hbuf + (size_t)n * M_TOK * H_DIM;
  const bf16* gA0 = hp + (size_t)(row0 + trow) * H_DIM + gk;
  const bf16* gA1 = gA0 + (size_t)32 * H_DIM;
  const bf16* gA2 = gA0 + (size_t)64 * H_DIM;
  const bf16* gA3 = gA0 + (size_t)96 * H_DIM;
  const bf16* gB0 = W2t + ((size_t)n * D_DIM + nt * 64 + trow) * H_DIM + gk;
  const bf16* gB1 = gB0 + (size_t)32 * H_DIM;

#define L2_STAGE(BUF, KT) do {                                   \
    const int ko = (KT) * 64;                                    \
    GLOAD16(gA0 + ko, &BUF[(0 * 256 + t) * 8]);                  \
    GLOAD16(gA1 + ko, &BUF[(1 * 256 + t) * 8]);                  \
    GLOAD16(gA2 + ko, &BUF[(2 * 256 + t) * 8]);                  \
    GLOAD16(gA3 + ko, &BUF[(3 * 256 + t) * 8]);                  \
    GLOAD16(gB0 + ko, &BUF[8192 + (0 * 256 + t) * 8]);           \
    GLOAD16(gB1 + ko, &BUF[8192 + (1 * 256 + t) * 8]);           \
  } while (0)

  const int lane = t & 63, wid = t >> 6;
  const int wm = wid >> 1, wn = wid & 1;
  const int l15 = lane & 15, lhi = lane >> 4, l7 = l15 & 7;

  f32x4 acc[4][2];
#pragma unroll
  for (int i = 0; i < 4; ++i)
#pragma unroll
    for (int j = 0; j < 2; ++j) acc[i][j] = (f32x4){0.f, 0.f, 0.f, 0.f};

#define L2_COMPUTE(BUF) do {                                                   \
    bf16x8 a[4][2], b[2][2];                                                   \
    _Pragma("unroll") for (int kk = 0; kk < 2; ++kk) {                         \
      const int sl = ((kk * 4 + lhi) ^ l7) * 8;                                \
      _Pragma("unroll") for (int fm = 0; fm < 4; ++fm)                         \
        a[fm][kk] = *reinterpret_cast<const bf16x8*>(                          \
            &BUF[(wm * 64 + fm * 16 + l15) * 64 + sl]);                        \
      _Pragma("unroll") for (int fn = 0; fn < 2; ++fn)                         \
        b[fn][kk] = *reinterpret_cast<const bf16x8*>(                          \
            &BUF[8192 + (wn * 32 + fn * 16 + l15) * 64 + sl]);                 \
    }                                                                          \
    _Pragma("unroll") for (int kk = 0; kk < 2; ++kk)                           \
    _Pragma("unroll") for (int fm = 0; fm < 4; ++fm)                           \
    _Pragma("unroll") for (int fn = 0; fn < 2; ++fn)                           \
      acc[fm][fn] = __builtin_amdgcn_mfma_f32_16x16x32_bf16(                   \
          a[fm][kk], b[fn][kk], acc[fm][fn], 0, 0, 0);                         \
  } while (0)

  L2_STAGE(L0, 0);
  __syncthreads();
  for (int it = 0; it < 8; ++it) {
    L2_STAGE(L1, 2 * it + 1);
    L2_COMPUTE(L0);
    __syncthreads();
    if (it < 7) L2_STAGE(L0, 2 * it + 2);
    L2_COMPUTE(L1);
    __syncthreads();
  }

#pragma unroll
  for (int fm = 0; fm < 4; ++fm)
#pragma unroll
    for (int r = 0; r < 4; ++r) {
      const int mrow = row0 + wm * 64 + fm * 16 + lhi * 4 + r;
      if (mrow < row0 + 128 && mrow - row0 + (row0) < c + 0 ? (mrow < c) : false) {}
      if (mrow < c) {
        const int tok = (n == N_EXP - 1) ? mrow : perm[n * M_TOK + mrow];
        const float wt = (n == N_EXP - 1) ? 1.f : wtok[tok];
        const size_t base = (size_t)tok * D_DIM + nt * 64 + wn * 32 + l15;
        atomicAdd(&out[base], wt * acc[fm][0][r]);
        atomicAdd(&out[base + 16], wt * acc[fm][1][r]);
      }
    }
#undef L2_STAGE
#undef L2_COMPUTE
}

extern "C" void kernel_launch(void* const* d_in, const int* in_sizes, int n_in,
                              void* d_out, int out_size, void* d_ws, size_t ws_size,
                              hipStream_t stream) {
  const float* x   = (const float*)d_in[0];   // [2,1024,1024] f32
  const float* Wg  = (const float*)d_in[1];   // [1024,8]
  const float* Wl1 = (const float*)d_in[2];   // [8,1024,2048]
  const float* Wl2 = (const float*)d_in[3];   // [8,1024,1024]
  float* out = (float*)d_out;                 // [2,1024,1024] f32

  char* ws = (char*)d_ws;
  int*   cnt    = (int*)(ws + 0);                      // 32 B
  float* wtok   = (float*)(ws + 1024);                 // 8 KB
  int*   perm   = (int*)(ws + 16384);                  // 64 KB
  int*   tmap   = (int*)(ws + 81920);                  // 320 B
  int*   ntiles = (int*)(ws + 83968);                  // 4 B
  bf16*  xb   = (bf16*)(ws + (1ull << 20));            // 4 MB
  bf16*  W1t  = (bf16*)(ws + (8ull << 20));            // 32 MB
  bf16*  W2t  = (bf16*)(ws + (40ull << 20));           // 16 MB
  bf16*  hbuf = (bf16*)(ws + (56ull << 20));           // 32 MB

  hipMemsetAsync(cnt, 0, N_EXP * sizeof(int), stream);
  hipMemsetAsync(out, 0, (size_t)M_TOK * D_DIM * sizeof(float), stream);

  convx_kernel<<<M_TOK * D_DIM / 8 / 256, 256, 0, stream>>>(x, xb);
  transconv_kernel<<<dim3(2 * H_DIM / 64, D_DIM / 64, N_EXP), 256, 0, stream>>>(
      Wl1, W1t, D_DIM, 2 * H_DIM);
  transconv_kernel<<<dim3(D_DIM / 64, H_DIM / 64, N_EXP), 256, 0, stream>>>(
      Wl2, W2t, H_DIM, D_DIM);
  routing_kernel<<<M_TOK / 4, 256, 0, stream>>>(x, Wg, wtok, cnt, perm);
  tilemap_kernel<<<1, 64, 0, stream>>>(cnt, tmap, ntiles);

  l1_kernel<<<dim3(16, MAXT), 256, 0, stream>>>(xb, W1t, perm, cnt, tmap, ntiles, hbuf);
  l2_kernel<<<dim3(16, MAXT), 256, 0, stream>>>(hbuf, W2t, perm, cnt, tmap, ntiles, wtok, out);
}

// Round 5
// 245.595 us; speedup vs baseline: 8.9097x; 1.0049x over previous
//
#include <hip/hip_runtime.h>
#include <hip/hip_bf16.h>
#include <math.h>

#define M_TOK 2048
#define D_DIM 1024
#define H_DIM 1024
#define N_EXP 8
#define N_ROUTED 7
#define MAXT 40

typedef __hip_bfloat16 bf16;
typedef float f32x4 __attribute__((ext_vector_type(4)));
typedef short bf16x8 __attribute__((ext_vector_type(8)));

#define GLOAD16(gp, lp)                                                     \
  __builtin_amdgcn_global_load_lds(                                         \
      (const __attribute__((address_space(1))) void*)(gp),                  \
      (__attribute__((address_space(3))) void*)(lp), 16, 0, 0)

// ---------------- routing + x->bf16 convert: 1 wave per token ----------------
__global__ __launch_bounds__(256)
void routing_kernel(const float* __restrict__ x,
                    const float* __restrict__ Wg,
                    bf16* __restrict__ xb,
                    float* __restrict__ w_out,
                    int* __restrict__ cnt,
                    int* __restrict__ perm) {
  const int lane = threadIdx.x & 63;
  const int m = blockIdx.x * 4 + (threadIdx.x >> 6);
  if (m >= M_TOK) return;
  float acc[N_EXP];
#pragma unroll
  for (int n = 0; n < N_EXP; ++n) acc[n] = 0.f;
  const float* xr = x + (size_t)m * D_DIM;
  bf16* xbr = xb + (size_t)m * D_DIM;
  for (int d = lane; d < D_DIM; d += 64) {
    const float xv = xr[d];
    xbr[d] = __float2bfloat16(xv);
    const float4 wa = *reinterpret_cast<const float4*>(Wg + (size_t)d * N_EXP);
    const float4 wb = *reinterpret_cast<const float4*>(Wg + (size_t)d * N_EXP + 4);
    acc[0] = fmaf(xv, wa.x, acc[0]);
    acc[1] = fmaf(xv, wa.y, acc[1]);
    acc[2] = fmaf(xv, wa.z, acc[2]);
    acc[3] = fmaf(xv, wa.w, acc[3]);
    acc[4] = fmaf(xv, wb.x, acc[4]);
    acc[5] = fmaf(xv, wb.y, acc[5]);
    acc[6] = fmaf(xv, wb.z, acc[6]);
    acc[7] = fmaf(xv, wb.w, acc[7]);
  }
#pragma unroll
  for (int n = 0; n < N_EXP; ++n) {
#pragma unroll
    for (int off = 32; off > 0; off >>= 1)
      acc[n] += __shfl_xor(acc[n], off, 64);
  }
  if (lane == 0) {
    int bi = 0;
    float bl = acc[0];
#pragma unroll
    for (int n = 1; n < N_ROUTED; ++n) {
      if (acc[n] > bl) { bl = acc[n]; bi = n; }
    }
    const float s = 1.f / (1.f + expf(-bl));
    w_out[m] = s / (s + 1e-9f);
    const int pos = atomicAdd(&cnt[bi], 1);
    perm[bi * M_TOK + pos] = m;
  }
}

// ---------------- tile map: compact active (expert,row0) tiles ----------------
__global__ void tilemap_kernel(const int* __restrict__ cnt,
                               int* __restrict__ tmap, int* __restrict__ ntiles) {
  if (threadIdx.x == 0 && blockIdx.x == 0) {
    int t = 0;
    for (int n = 0; n < N_ROUTED; ++n) {
      const int c = cnt[n];
      for (int r = 0; r < c; r += 128) { tmap[2 * t] = n; tmap[2 * t + 1] = r; ++t; }
    }
    for (int r = 0; r < M_TOK; r += 128) { tmap[2 * t] = N_EXP - 1; tmap[2 * t + 1] = r; ++t; }
    ntiles[0] = t;
    for (int u = t; u < MAXT; ++u) { tmap[2 * u] = 0; tmap[2 * u + 1] = 0; }
  }
}

// ---------- f32 [z][R][C] -> bf16 [z][C][R], 64x64 tile, 16B stores ----------
__global__ __launch_bounds__(256)
void transconv_kernel(const float* __restrict__ in, bf16* __restrict__ outb,
                      int R, int C) {
  __shared__ float tile[64][65];
  const int t = threadIdx.x;
  const float* inp = in + (size_t)blockIdx.z * R * C;
  bf16* outp = outb + (size_t)blockIdx.z * R * C;
  const int c0 = blockIdx.x * 64, r0 = blockIdx.y * 64;
  const int lr = t >> 4, lc4 = (t & 15) * 4;
#pragma unroll
  for (int rep = 0; rep < 4; ++rep) {
    const float4 v = *reinterpret_cast<const float4*>(
        inp + (size_t)(r0 + lr + rep * 16) * C + c0 + lc4);
    float* dst = &tile[lr + rep * 16][lc4];
    dst[0] = v.x; dst[1] = v.y; dst[2] = v.z; dst[3] = v.w;
  }
  __syncthreads();
  const int seg = t & 7;
#pragma unroll
  for (int rep = 0; rep < 2; ++rep) {
    const int oc = (t >> 3) + rep * 32;
    union { bf16 h[8]; uint4 q; } u;
#pragma unroll
    for (int j = 0; j < 8; ++j) u.h[j] = __float2bfloat16(tile[seg * 8 + j][oc]);
    *reinterpret_cast<uint4*>(outp + (size_t)(c0 + oc) * R + r0 + seg * 8) = u.q;
  }
}

// ================= layer 1: h = silu(x@W1g) * (x@W1u) =================
// BM=128 rows, BN=32 h-cols (32 g + 32 u B-rows), BK=64. 4 waves 2x2
// (wave = 64 rows x 16 cols). Double-buffered LDS, 1 barrier per K-step.
// LDS elem layout per buffer: A[128][64] @0, Bg[32][64] @8192, Bu @10240.
// Swizzle: logical (row, slot s of 8 bf16) stored at slot s^(row&7).
__global__ __launch_bounds__(256, 3)
void l1_kernel(const bf16* __restrict__ xb,
               const bf16* __restrict__ W1t,   // [8][2048][1024]
               const int* __restrict__ perm,
               const int* __restrict__ cnt,
               const int* __restrict__ tmap,
               const int* __restrict__ ntiles,
               bf16* __restrict__ hbuf) {      // [8][2048][1024]
  const int ti = blockIdx.y;
  if (ti >= ntiles[0]) return;
  const int n = tmap[2 * ti], row0 = tmap[2 * ti + 1];
  const int nt = blockIdx.x;          // 0..31, 32 h-cols each
  const int c = (n == N_EXP - 1) ? M_TOK : cnt[n];

  __shared__ bf16 L0[12288];
  __shared__ bf16 L1[12288];

  const int t = threadIdx.x;
  const int trow = t >> 3;                       // row within 32-row round
  const int gk = ((t & 7) ^ (trow & 7)) * 8;     // swizzled source k-offset

  int tokr[4];
#pragma unroll
  for (int p = 0; p < 4; ++p) {
    const int lr = row0 + p * 32 + trow;
    tokr[p] = (n == N_EXP - 1) ? lr : perm[n * M_TOK + (lr < c ? lr : row0)];
  }
  const bf16* gA0 = xb + (size_t)tokr[0] * D_DIM + gk;
  const bf16* gA1 = xb + (size_t)tokr[1] * D_DIM + gk;
  const bf16* gA2 = xb + (size_t)tokr[2] * D_DIM + gk;
  const bf16* gA3 = xb + (size_t)tokr[3] * D_DIM + gk;
  const bf16* gBg = W1t + ((size_t)n * 2048 + nt * 32 + trow) * D_DIM + gk;
  const bf16* gBu = gBg + (size_t)H_DIM * D_DIM;

#define L1_STAGE(BUF, KT) do {                                   \
    const int ko = (KT) * 64;                                    \
    GLOAD16(gA0 + ko, &BUF[(0 * 256 + t) * 8]);                  \
    GLOAD16(gA1 + ko, &BUF[(1 * 256 + t) * 8]);                  \
    GLOAD16(gA2 + ko, &BUF[(2 * 256 + t) * 8]);                  \
    GLOAD16(gA3 + ko, &BUF[(3 * 256 + t) * 8]);                  \
    GLOAD16(gBg + ko, &BUF[8192 + t * 8]);                       \
    GLOAD16(gBu + ko, &BUF[10240 + t * 8]);                      \
  } while (0)

  const int lane = t & 63, wid = t >> 6;
  const int wm = wid >> 1, wn = wid & 1;
  const int l15 = lane & 15, lhi = lane >> 4, l7 = l15 & 7;

  f32x4 accg[4], accu[4];
#pragma unroll
  for (int i = 0; i < 4; ++i) {
    accg[i] = (f32x4){0.f, 0.f, 0.f, 0.f};
    accu[i] = (f32x4){0.f, 0.f, 0.f, 0.f};
  }

#define L1_COMPUTE(BUF) do {                                                   \
    bf16x8 a[4][2], bg[2], bu[2];                                              \
    _Pragma("unroll") for (int kk = 0; kk < 2; ++kk) {                         \
      const int sl = ((kk * 4 + lhi) ^ l7) * 8;                                \
      _Pragma("unroll") for (int fm = 0; fm < 4; ++fm)                         \
        a[fm][kk] = *reinterpret_cast<const bf16x8*>(                          \
            &BUF[(wm * 64 + fm * 16 + l15) * 64 + sl]);                        \
      bg[kk] = *reinterpret_cast<const bf16x8*>(                               \
          &BUF[8192 + (wn * 16 + l15) * 64 + sl]);                             \
      bu[kk] = *reinterpret_cast<const bf16x8*>(                               \
          &BUF[10240 + (wn * 16 + l15) * 64 + sl]);                            \
    }                                                                          \
    _Pragma("unroll") for (int kk = 0; kk < 2; ++kk)                           \
    _Pragma("unroll") for (int fm = 0; fm < 4; ++fm) {                         \
      accg[fm] = __builtin_amdgcn_mfma_f32_16x16x32_bf16(                      \
          a[fm][kk], bg[kk], accg[fm], 0, 0, 0);                               \
      accu[fm] = __builtin_amdgcn_mfma_f32_16x16x32_bf16(                      \
          a[fm][kk], bu[kk], accu[fm], 0, 0, 0);                               \
    }                                                                          \
  } while (0)

  L1_STAGE(L0, 0);
  __syncthreads();
  for (int it = 0; it < 8; ++it) {
    L1_STAGE(L1, 2 * it + 1);
    L1_COMPUTE(L0);
    __syncthreads();
    if (it < 7) L1_STAGE(L0, 2 * it + 2);
    L1_COMPUTE(L1);
    __syncthreads();
  }

  bf16* hp = hbuf + (size_t)n * M_TOK * H_DIM;
  const int col = nt * 32 + wn * 16 + l15;
#pragma unroll
  for (int fm = 0; fm < 4; ++fm)
#pragma unroll
    for (int r = 0; r < 4; ++r) {
      const int mrow = row0 + wm * 64 + fm * 16 + lhi * 4 + r;
      const float g = accg[fm][r];
      const float u = accu[fm][r];
      const float h = g * u / (1.f + __expf(-g));
      hp[(size_t)mrow * H_DIM + col] = __float2bfloat16(h);
    }
#undef L1_STAGE
#undef L1_COMPUTE
}

// ================= layer 2: out += w * (h @ W2) =================
// BM=128, BN=32, BK=64. 4 waves 2x2 (wave 64x16). Dbuf, 1 barrier/K-step.
// LDS per buffer: A[128][64] @0, B[32][64] @8192.
__global__ __launch_bounds__(256, 3)
void l2_kernel(const bf16* __restrict__ hbuf,
               const bf16* __restrict__ W2t,    // [8][1024 d][1024 h]
               const int* __restrict__ perm,
               const int* __restrict__ cnt,
               const int* __restrict__ tmap,
               const int* __restrict__ ntiles,
               const float* __restrict__ wtok,
               float* __restrict__ out) {
  const int ti = blockIdx.y;
  if (ti >= ntiles[0]) return;
  const int n = tmap[2 * ti], row0 = tmap[2 * ti + 1];
  const int nt = blockIdx.x;          // 0..31, 32 d-cols each
  const int c = (n == N_EXP - 1) ? M_TOK : cnt[n];

  __shared__ bf16 L0[10240];
  __shared__ bf16 L1[10240];

  const int t = threadIdx.x;
  const int trow = t >> 3;
  const int gk = ((t & 7) ^ (trow & 7)) * 8;

  const bf16* hp = hbuf + (size_t)n * M_TOK * H_DIM;
  const bf16* gA0 = hp + (size_t)(row0 + trow) * H_DIM + gk;
  const bf16* gA1 = gA0 + (size_t)32 * H_DIM;
  const bf16* gA2 = gA0 + (size_t)64 * H_DIM;
  const bf16* gA3 = gA0 + (size_t)96 * H_DIM;
  const bf16* gB = W2t + ((size_t)n * D_DIM + nt * 32 + trow) * H_DIM + gk;

#define L2_STAGE(BUF, KT) do {                                   \
    const int ko = (KT) * 64;                                    \
    GLOAD16(gA0 + ko, &BUF[(0 * 256 + t) * 8]);                  \
    GLOAD16(gA1 + ko, &BUF[(1 * 256 + t) * 8]);                  \
    GLOAD16(gA2 + ko, &BUF[(2 * 256 + t) * 8]);                  \
    GLOAD16(gA3 + ko, &BUF[(3 * 256 + t) * 8]);                  \
    GLOAD16(gB + ko, &BUF[8192 + t * 8]);                        \
  } while (0)

  const int lane = t & 63, wid = t >> 6;
  const int wm = wid >> 1, wn = wid & 1;
  const int l15 = lane & 15, lhi = lane >> 4, l7 = l15 & 7;

  f32x4 acc[4];
#pragma unroll
  for (int i = 0; i < 4; ++i) acc[i] = (f32x4){0.f, 0.f, 0.f, 0.f};

#define L2_COMPUTE(BUF) do {                                                   \
    bf16x8 a[4][2], b[2];                                                      \
    _Pragma("unroll") for (int kk = 0; kk < 2; ++kk) {                         \
      const int sl = ((kk * 4 + lhi) ^ l7) * 8;                                \
      _Pragma("unroll") for (int fm = 0; fm < 4; ++fm)                         \
        a[fm][kk] = *reinterpret_cast<const bf16x8*>(                          \
            &BUF[(wm * 64 + fm * 16 + l15) * 64 + sl]);                        \
      b[kk] = *reinterpret_cast<const bf16x8*>(                                \
          &BUF[8192 + (wn * 16 + l15) * 64 + sl]);                             \
    }                                                                          \
    _Pragma("unroll") for (int kk = 0; kk < 2; ++kk)                           \
    _Pragma("unroll") for (int fm = 0; fm < 4; ++fm)                           \
      acc[fm] = __builtin_amdgcn_mfma_f32_16x16x32_bf16(                       \
          a[fm][kk], b[kk], acc[fm], 0, 0, 0);                                 \
  } while (0)

  L2_STAGE(L0, 0);
  __syncthreads();
  for (int it = 0; it < 8; ++it) {
    L2_STAGE(L1, 2 * it + 1);
    L2_COMPUTE(L0);
    __syncthreads();
    if (it < 7) L2_STAGE(L0, 2 * it + 2);
    L2_COMPUTE(L1);
    __syncthreads();
  }

  const int colb = nt * 32 + wn * 16 + l15;
#pragma unroll
  for (int fm = 0; fm < 4; ++fm)
#pragma unroll
    for (int r = 0; r < 4; ++r) {
      const int mrow = row0 + wm * 64 + fm * 16 + lhi * 4 + r;
      if (mrow < c) {
        const int tok = (n == N_EXP - 1) ? mrow : perm[n * M_TOK + mrow];
        const float wt = (n == N_EXP - 1) ? 1.f : wtok[tok];
        atomicAdd(&out[(size_t)tok * D_DIM + colb], wt * acc[fm][r]);
      }
    }
#undef L2_STAGE
#undef L2_COMPUTE
}

extern "C" void kernel_launch(void* const* d_in, const int* in_sizes, int n_in,
                              void* d_out, int out_size, void* d_ws, size_t ws_size,
                              hipStream_t stream) {
  const float* x   = (const float*)d_in[0];   // [2,1024,1024] f32
  const float* Wg  = (const float*)d_in[1];   // [1024,8]
  const float* Wl1 = (const float*)d_in[2];   // [8,1024,2048]
  const float* Wl2 = (const float*)d_in[3];   // [8,1024,1024]
  float* out = (float*)d_out;                 // [2,1024,1024] f32

  char* ws = (char*)d_ws;
  int*   cnt    = (int*)(ws + 0);                      // 32 B
  float* wtok   = (float*)(ws + 1024);                 // 8 KB
  int*   perm   = (int*)(ws + 16384);                  // 64 KB
  int*   tmap   = (int*)(ws + 81920);                  // 320 B
  int*   ntiles = (int*)(ws + 83968);                  // 4 B
  bf16*  xb   = (bf16*)(ws + (1ull << 20));            // 4 MB
  bf16*  W1t  = (bf16*)(ws + (8ull << 20));            // 32 MB
  bf16*  W2t  = (bf16*)(ws + (40ull << 20));           // 16 MB
  bf16*  hbuf = (bf16*)(ws + (56ull << 20));           // 32 MB

  hipMemsetAsync(cnt, 0, N_EXP * sizeof(int), stream);
  hipMemsetAsync(out, 0, (size_t)M_TOK * D_DIM * sizeof(float), stream);

  transconv_kernel<<<dim3(2 * H_DIM / 64, D_DIM / 64, N_EXP), 256, 0, stream>>>(
      Wl1, W1t, D_DIM, 2 * H_DIM);
  transconv_kernel<<<dim3(D_DIM / 64, H_DIM / 64, N_EXP), 256, 0, stream>>>(
      Wl2, W2t, H_DIM, D_DIM);
  routing_kernel<<<M_TOK / 4, 256, 0, stream>>>(x, Wg, xb, wtok, cnt, perm);
  tilemap_kernel<<<1, 64, 0, stream>>>(cnt, tmap, ntiles);

  l1_kernel<<<dim3(32, MAXT), 256, 0, stream>>>(xb, W1t, perm, cnt, tmap, ntiles, hbuf);
  l2_kernel<<<dim3(32, MAXT), 256, 0, stream>>>(hbuf, W2t, perm, cnt, tmap, ntiles, wtok, out);
}